// Round 1
// baseline (354.041 us; speedup 1.0000x reference)
//
#include <hip/hip_runtime.h>
#include <math.h>

#define BB 64
#define NN 256
#define IN_F 128
#define OF 128
#define HH 4
#define NEG_SLOPE 0.2f

// ---------------- K1: Wh = h @ W, stored (B,H,N,F) ----------------
__global__ __launch_bounds__(256) void k1_wh(const float* __restrict__ h,
                                             const float* __restrict__ W,
                                             float* __restrict__ Wh) {
    __shared__ float hl[16][IN_F];   // 8 KB
    int blk = blockIdx.x;            // B * 16
    int b = blk >> 4;
    int n0 = (blk & 15) * 16;
    int t = threadIdx.x;
    {   // stage 16 rows of h: 2048 floats = 512 float4
        const float4* src = (const float4*)(h + ((size_t)b * NN + n0) * IN_F);
        float4* dst = (float4*)&hl[0][0];
        dst[t] = src[t];
        dst[t + 256] = src[t + 256];
    }
    __syncthreads();
    int half = t >> 7;        // row half
    int cq = t & 127;         // output col quad, c = cq*4..cq*4+3
    float4 acc[8];
#pragma unroll
    for (int i = 0; i < 8; i++) acc[i] = make_float4(0.f, 0.f, 0.f, 0.f);
    const float4* Wv = (const float4*)W;  // row k: 512 floats = 128 float4
#pragma unroll 4
    for (int k = 0; k < IN_F; k++) {
        float4 wv = Wv[k * 128 + cq];
#pragma unroll
        for (int i = 0; i < 8; i++) {
            float hv = hl[half * 8 + i][k];   // wave-uniform -> broadcast
            acc[i].x += hv * wv.x; acc[i].y += hv * wv.y;
            acc[i].z += hv * wv.z; acc[i].w += hv * wv.w;
        }
    }
    int head = cq >> 5;
    int f4 = cq & 31;
#pragma unroll
    for (int i = 0; i < 8; i++) {
        int n = n0 + half * 8 + i;
        float4* dst = (float4*)(Wh + (((size_t)b * HH + head) * NN + n) * OF);
        dst[f4] = acc[i];
    }
}

// ---------------- K1b: per-node scalars e_i, e_j, s_proj, s_sim ----------------
__global__ __launch_bounds__(256) void k1b_scalars(const float* __restrict__ Wh,
        const float* __restrict__ a, const float* __restrict__ w_proj,
        const float* __restrict__ w_sim,
        float* __restrict__ ei, float* __restrict__ ej,
        float* __restrict__ sp, float* __restrict__ ss) {
    int wave = threadIdx.x >> 6, lane = threadIdx.x & 63;
    int idx = blockIdx.x * 4 + wave;           // (b*H + h)*N + n
    int hh = (idx >> 8) & 3;
    const float2* row = (const float2*)(Wh + (size_t)idx * OF);
    float2 v = row[lane];
    const float2* a1 = (const float2*)(a + hh * 2 * OF);
    const float2* a2 = (const float2*)(a + hh * 2 * OF + OF);
    float2 a1v = a1[lane], a2v = a2[lane];
    float2 wpv = ((const float2*)w_proj)[lane];
    float2 wsv = ((const float2*)w_sim)[lane];
    float s0 = v.x * a1v.x + v.y * a1v.y;
    float s1 = v.x * a2v.x + v.y * a2v.y;
    float s2 = v.x * wpv.x + v.y * wpv.y;
    float s3 = v.x * wsv.x + v.y * wsv.y;
#pragma unroll
    for (int off = 32; off; off >>= 1) {
        s0 += __shfl_down(s0, off);
        s1 += __shfl_down(s1, off);
        s2 += __shfl_down(s2, off);
        s3 += __shfl_down(s3, off);
    }
    if (lane == 0) { ei[idx] = s0; ej[idx] = s1; sp[idx] = s2; ss[idx] = s3; }
}

// ---------------- K2: e-matrix + softmax + PV ----------------
__global__ __launch_bounds__(256) void k2_attn(
        const float* __restrict__ proj, const float* __restrict__ sim,
        const int* __restrict__ qm, const float* __restrict__ qbias,
        const float* __restrict__ ei, const float* __restrict__ ej,
        const float* __restrict__ sp, const float* __restrict__ ss,
        const float* __restrict__ Wh, float* __restrict__ hp) {
    __shared__ float ejs[HH][NN];        // 4 KB
    __shared__ float eis[HH][16], sps[HH][16], sss[HH][16];
    __shared__ float attn[HH][16][NN];   // 64 KB
    __shared__ float wred[2][4][HH];
    __shared__ float qb_s[16];
    int blk = blockIdx.x;                // B * 16
    int b = blk >> 4;
    int i0 = (blk & 15) * 16;
    int t = threadIdx.x;
    int wave = t >> 6, lane = t & 63;
    for (int c = t; c < HH * NN; c += 256) {
        int hh = c >> 8, j = c & 255;
        ejs[hh][j] = ej[((size_t)b * HH + hh) * NN + j];
    }
    if (t < 64) {
        int hh = t >> 4, ii = t & 15;
        size_t base = ((size_t)b * HH + hh) * NN + i0 + ii;
        eis[hh][ii] = ei[base]; sps[hh][ii] = sp[base]; sss[hh][ii] = ss[base];
    }
    if (t < 16) qb_s[t] = qbias[t];
    __syncthreads();

    int j = t;
    const int2* qmp = (const int2*)qm;
    for (int ii = 0; ii < 16; ii++) {
        int i = i0 + ii;
        size_t rbase = ((size_t)b * NN + i) * NN + j;
        float P = proj[rbase];
        float S = sim[rbase];
        int2 q = qmp[rbase];
        float qb = qb_s[q.x * 4 + q.y];
        float e[HH];
#pragma unroll
        for (int hh = 0; hh < HH; hh++) {
            float x = eis[hh][ii] + ejs[hh][j];
            x = x > 0.f ? x : NEG_SLOPE * x;
            e[hh] = x + sps[hh][ii] * P + sss[hh][ii] * S + qb;
        }
        float m[HH];
#pragma unroll
        for (int hh = 0; hh < HH; hh++) m[hh] = e[hh];
#pragma unroll
        for (int off = 32; off; off >>= 1)
#pragma unroll
            for (int hh = 0; hh < HH; hh++)
                m[hh] = fmaxf(m[hh], __shfl_xor(m[hh], off));
        if (lane == 0)
            for (int hh = 0; hh < HH; hh++) wred[0][wave][hh] = m[hh];
        __syncthreads();
        float ex[HH], sm[HH];
#pragma unroll
        for (int hh = 0; hh < HH; hh++) {
            float mx = fmaxf(fmaxf(wred[0][0][hh], wred[0][1][hh]),
                             fmaxf(wred[0][2][hh], wred[0][3][hh]));
            ex[hh] = __expf(e[hh] - mx);
            sm[hh] = ex[hh];
        }
#pragma unroll
        for (int off = 32; off; off >>= 1)
#pragma unroll
            for (int hh = 0; hh < HH; hh++) sm[hh] += __shfl_xor(sm[hh], off);
        if (lane == 0)
            for (int hh = 0; hh < HH; hh++) wred[1][wave][hh] = sm[hh];
        __syncthreads();
#pragma unroll
        for (int hh = 0; hh < HH; hh++) {
            float s = wred[1][0][hh] + wred[1][1][hh] + wred[1][2][hh] + wred[1][3][hh];
            attn[hh][ii][j] = ex[hh] / s;
        }
        __syncthreads();   // protect wred before next row reuses it
    }

    // phase C: h_prime rows = attn @ Wh
    int half = t >> 7;
    int hh = (t >> 5) & 3;
    int fq = t & 31;
    float4 acc[8];
#pragma unroll
    for (int i = 0; i < 8; i++) acc[i] = make_float4(0.f, 0.f, 0.f, 0.f);
    const float4* whbase = (const float4*)(Wh + (((size_t)b * HH + hh) * NN) * OF);
    for (int jj = 0; jj < NN; jj++) {
        float4 wv = whbase[jj * 32 + fq];
#pragma unroll
        for (int i = 0; i < 8; i++) {
            float av = attn[hh][half * 8 + i][jj];  // broadcast (2 addrs/wave)
            acc[i].x += av * wv.x; acc[i].y += av * wv.y;
            acc[i].z += av * wv.z; acc[i].w += av * wv.w;
        }
    }
#pragma unroll
    for (int i = 0; i < 8; i++) {
        int n = i0 + half * 8 + i;
        float4* dst = (float4*)(hp + (((size_t)b * NN + n) * HH + hh) * OF);
        dst[fq] = acc[i];
    }
}

// ---------------- K3: out = elu(hp @ W_concat) ----------------
__global__ __launch_bounds__(256) void k3_out(const float* __restrict__ hp,
        const float* __restrict__ Wc, float* __restrict__ out) {
    __shared__ float hps[32][516];   // pad 4 -> 4-way row-group reads hit distinct banks
    int blk = blockIdx.x;            // B * 8
    int b = blk >> 3;
    int n0 = (blk & 7) * 32;
    int t = threadIdx.x;
    const float4* src = (const float4*)(hp + ((size_t)b * NN + n0) * (HH * OF));
#pragma unroll
    for (int e = 0; e < 16; e++) {
        int li4 = e * 256 + t;          // 0..4095 float4, lanes consecutive
        float4 v = src[li4];
        int row = li4 >> 7;             // 128 float4 per row
        int col = (li4 & 127) * 4;
        *(float4*)&hps[row][col] = v;
    }
    __syncthreads();
    int iq = t >> 4;      // 16 row-pairs -> 32 rows
    int fo = t & 15;      // 8 floats: f = fo*8
    float4 acc[2][2];
#pragma unroll
    for (int r = 0; r < 2; r++)
        for (int c = 0; c < 2; c++) acc[r][c] = make_float4(0.f, 0.f, 0.f, 0.f);
    const float4* wcv = (const float4*)Wc;  // row k: 128 floats = 32 float4
    for (int k = 0; k < 512; k++) {
        float4 w0 = wcv[k * 32 + fo * 2];
        float4 w1 = wcv[k * 32 + fo * 2 + 1];
        float h0 = hps[iq * 2][k];
        float h1 = hps[iq * 2 + 1][k];
        acc[0][0].x += h0 * w0.x; acc[0][0].y += h0 * w0.y; acc[0][0].z += h0 * w0.z; acc[0][0].w += h0 * w0.w;
        acc[0][1].x += h0 * w1.x; acc[0][1].y += h0 * w1.y; acc[0][1].z += h0 * w1.z; acc[0][1].w += h0 * w1.w;
        acc[1][0].x += h1 * w0.x; acc[1][0].y += h1 * w0.y; acc[1][0].z += h1 * w0.z; acc[1][0].w += h1 * w0.w;
        acc[1][1].x += h1 * w1.x; acc[1][1].y += h1 * w1.y; acc[1][1].z += h1 * w1.z; acc[1][1].w += h1 * w1.w;
    }
#pragma unroll
    for (int r = 0; r < 2; r++) {
        int n = n0 + iq * 2 + r;
        float4* dst = (float4*)(out + ((size_t)b * NN + n) * OF);
#pragma unroll
        for (int c = 0; c < 2; c++) {
            float4 v = acc[r][c];
            v.x = v.x > 0.f ? v.x : expm1f(v.x);
            v.y = v.y > 0.f ? v.y : expm1f(v.y);
            v.z = v.z > 0.f ? v.z : expm1f(v.z);
            v.w = v.w > 0.f ? v.w : expm1f(v.w);
            dst[fo * 2 + c] = v;
        }
    }
}

extern "C" void kernel_launch(void* const* d_in, const int* in_sizes, int n_in,
                              void* d_out, int out_size, void* d_ws, size_t ws_size,
                              hipStream_t stream) {
    const float* h      = (const float*)d_in[0];
    const float* proj   = (const float*)d_in[1];
    const float* sim    = (const float*)d_in[2];
    const int*   qm     = (const int*)d_in[3];
    const float* W      = (const float*)d_in[4];
    const float* a      = (const float*)d_in[5];
    const float* w_proj = (const float*)d_in[6];
    const float* w_sim  = (const float*)d_in[7];
    const float* qbias  = (const float*)d_in[8];
    const float* Wc     = (const float*)d_in[9];
    float* out = (float*)d_out;

    const size_t whElems = (size_t)BB * HH * NN * OF;   // 8.39M
    float* Wh = (float*)d_ws;
    float* hp = Wh + whElems;
    float* ei = hp + whElems;
    float* ej = ei + (size_t)BB * HH * NN;
    float* sp = ej + (size_t)BB * HH * NN;
    float* ss = sp + (size_t)BB * HH * NN;

    k1_wh<<<BB * 16, 256, 0, stream>>>(h, W, Wh);
    k1b_scalars<<<BB * HH * NN / 4, 256, 0, stream>>>(Wh, a, w_proj, w_sim, ei, ej, sp, ss);
    k2_attn<<<BB * 16, 256, 0, stream>>>(proj, sim, qm, qbias, ei, ej, sp, ss, Wh, hp);
    k3_out<<<BB * 8, 256, 0, stream>>>(hp, Wc, out);
}

// Round 2
// 307.680 us; speedup vs baseline: 1.1507x; 1.1507x over previous
//
#include <hip/hip_runtime.h>
#include <math.h>

#define BB 64
#define NN 256
#define IN_F 128
#define OF 128
#define HH 4
#define NEG_SLOPE 0.2f

// float -> bf16 bits, round-to-nearest-even (x >= 0, finite)
__device__ inline unsigned short f2bf(float x) {
    unsigned u = __float_as_uint(x);
    u += 0x7fff + ((u >> 16) & 1);
    return (unsigned short)(u >> 16);
}

// ---------------- K1: Wh = h @ W (B,H,N,F) + fused per-node scalars ----------------
__global__ __launch_bounds__(256) void k1_wh(const float* __restrict__ h,
        const float* __restrict__ W, const float* __restrict__ a,
        const float* __restrict__ w_proj, const float* __restrict__ w_sim,
        float* __restrict__ Wh, float* __restrict__ ei, float* __restrict__ ej,
        float* __restrict__ sp, float* __restrict__ ss) {
    __shared__ float hl[16][IN_F];   // 8 KB
    int blk = blockIdx.x;            // B * 16
    int b = blk >> 4;
    int n0 = (blk & 15) * 16;
    int t = threadIdx.x;
    {   // stage 16 rows of h: 2048 floats = 512 float4
        const float4* src = (const float4*)(h + ((size_t)b * NN + n0) * IN_F);
        float4* dst = (float4*)&hl[0][0];
        dst[t] = src[t];
        dst[t + 256] = src[t + 256];
    }
    __syncthreads();
    int half = t >> 7;        // row half
    int cq = t & 127;         // output col quad, c = cq*4..cq*4+3
    float4 acc[8];
#pragma unroll
    for (int i = 0; i < 8; i++) acc[i] = make_float4(0.f, 0.f, 0.f, 0.f);
    const float4* Wv = (const float4*)W;  // row k: 512 floats = 128 float4
#pragma unroll 4
    for (int k = 0; k < IN_F; k++) {
        float4 wv = Wv[k * 128 + cq];
#pragma unroll
        for (int i = 0; i < 8; i++) {
            float hv = hl[half * 8 + i][k];   // wave-uniform -> broadcast
            acc[i].x += hv * wv.x; acc[i].y += hv * wv.y;
            acc[i].z += hv * wv.z; acc[i].w += hv * wv.w;
        }
    }
    int head = cq >> 5;
    int f4 = cq & 31;
    int f0 = f4 * 4;
#pragma unroll
    for (int i = 0; i < 8; i++) {
        int n = n0 + half * 8 + i;
        float4* dst = (float4*)(Wh + (((size_t)b * HH + head) * NN + n) * OF);
        dst[f4] = acc[i];
    }
    // fused scalars: e_i, e_j, s_proj, s_sim  (reduce over 32-lane f-group)
    float4 a1v = *(const float4*)&a[head * 2 * OF + f0];
    float4 a2v = *(const float4*)&a[head * 2 * OF + OF + f0];
    float4 wpv = *(const float4*)&w_proj[f0];
    float4 wsv = *(const float4*)&w_sim[f0];
    int lane = t & 63;
#pragma unroll
    for (int i = 0; i < 8; i++) {
        float p0 = acc[i].x * a1v.x + acc[i].y * a1v.y + acc[i].z * a1v.z + acc[i].w * a1v.w;
        float p1 = acc[i].x * a2v.x + acc[i].y * a2v.y + acc[i].z * a2v.z + acc[i].w * a2v.w;
        float p2 = acc[i].x * wpv.x + acc[i].y * wpv.y + acc[i].z * wpv.z + acc[i].w * wpv.w;
        float p3 = acc[i].x * wsv.x + acc[i].y * wsv.y + acc[i].z * wsv.z + acc[i].w * wsv.w;
#pragma unroll
        for (int off = 16; off; off >>= 1) {
            p0 += __shfl_down(p0, off, 32);
            p1 += __shfl_down(p1, off, 32);
            p2 += __shfl_down(p2, off, 32);
            p3 += __shfl_down(p3, off, 32);
        }
        if ((lane & 31) == 0) {
            int n = n0 + half * 8 + i;
            size_t idx = ((size_t)b * HH + head) * NN + n;
            ei[idx] = p0; ej[idx] = p1; sp[idx] = p2; ss[idx] = p3;
        }
    }
}

// ---------------- K2: e + softmax (wave-per-row) + PV + W_concat + ELU ----------------
__global__ __launch_bounds__(256) void k2_fused(
        const float* __restrict__ proj, const float* __restrict__ sim,
        const int* __restrict__ qm, const float* __restrict__ qbias,
        const float* __restrict__ ei, const float* __restrict__ ej,
        const float* __restrict__ sp, const float* __restrict__ ss,
        const float* __restrict__ Wh, const float* __restrict__ Wc,
        float* __restrict__ out) {
    __shared__ __align__(16) float big[8256];   // attn bf16 [4][16][256] (32768B) / hp [16][516]
    __shared__ __align__(16) float ejs[HH][NN]; // 4 KB
    __shared__ float eis[HH][16], sps[HH][16], sss[HH][16];
    __shared__ float qb_s[16];
    auto at = reinterpret_cast<unsigned short (*)[16][256]>(big);

    int blk = blockIdx.x;                // B * 16
    int b = blk >> 4;
    int i0 = (blk & 15) * 16;
    int t = threadIdx.x;
    int wave = t >> 6, lane = t & 63;

    for (int c = t; c < HH * NN; c += 256) {
        int hh = c >> 8, j = c & 255;
        ejs[hh][j] = ej[((size_t)b * HH + hh) * NN + j];
    }
    if (t < 64) {
        int hh = t >> 4, ii = t & 15;
        size_t base = ((size_t)b * HH + hh) * NN + i0 + ii;
        eis[hh][ii] = ei[base]; sps[hh][ii] = sp[base]; sss[hh][ii] = ss[base];
    }
    if (t < 16) qb_s[t] = qbias[t];
    __syncthreads();

    // ---- phase B: each wave owns rows ii = wave*4 .. wave*4+3; lane owns j = lane*4..+3
    int j0 = lane * 4;
    for (int rr = 0; rr < 4; rr++) {
        int ii = wave * 4 + rr;
        int i = i0 + ii;
        size_t rb = ((size_t)b * NN + i) * NN + j0;
        float4 P4 = *(const float4*)&proj[rb];
        float4 S4 = *(const float4*)&sim[rb];
        int4 q0 = *(const int4*)&qm[rb * 2];
        int4 q1 = *(const int4*)&qm[rb * 2 + 4];
        float qb0 = qb_s[q0.x * 4 + q0.y], qb1 = qb_s[q0.z * 4 + q0.w];
        float qb2 = qb_s[q1.x * 4 + q1.y], qb3 = qb_s[q1.z * 4 + q1.w];
        float e[HH][4];
#pragma unroll
        for (int hh = 0; hh < HH; hh++) {
            float4 ej4 = *(const float4*)&ejs[hh][j0];
            float bi = eis[hh][ii], spv = sps[hh][ii], ssv = sss[hh][ii];
            float x;
            x = bi + ej4.x; x = x > 0.f ? x : NEG_SLOPE * x; e[hh][0] = x + spv * P4.x + ssv * S4.x + qb0;
            x = bi + ej4.y; x = x > 0.f ? x : NEG_SLOPE * x; e[hh][1] = x + spv * P4.y + ssv * S4.y + qb1;
            x = bi + ej4.z; x = x > 0.f ? x : NEG_SLOPE * x; e[hh][2] = x + spv * P4.z + ssv * S4.z + qb2;
            x = bi + ej4.w; x = x > 0.f ? x : NEG_SLOPE * x; e[hh][3] = x + spv * P4.w + ssv * S4.w + qb3;
        }
        float m[HH];
#pragma unroll
        for (int hh = 0; hh < HH; hh++)
            m[hh] = fmaxf(fmaxf(e[hh][0], e[hh][1]), fmaxf(e[hh][2], e[hh][3]));
#pragma unroll
        for (int off = 32; off; off >>= 1)
#pragma unroll
            for (int hh = 0; hh < HH; hh++)
                m[hh] = fmaxf(m[hh], __shfl_xor(m[hh], off));
        float s[HH];
#pragma unroll
        for (int hh = 0; hh < HH; hh++) {
            e[hh][0] = __expf(e[hh][0] - m[hh]);
            e[hh][1] = __expf(e[hh][1] - m[hh]);
            e[hh][2] = __expf(e[hh][2] - m[hh]);
            e[hh][3] = __expf(e[hh][3] - m[hh]);
            s[hh] = (e[hh][0] + e[hh][1]) + (e[hh][2] + e[hh][3]);
        }
#pragma unroll
        for (int off = 32; off; off >>= 1)
#pragma unroll
            for (int hh = 0; hh < HH; hh++)
                s[hh] += __shfl_xor(s[hh], off);
#pragma unroll
        for (int hh = 0; hh < HH; hh++) {
            float inv = 1.0f / s[hh];
            ushort4 pk;
            pk.x = f2bf(e[hh][0] * inv);
            pk.y = f2bf(e[hh][1] * inv);
            pk.z = f2bf(e[hh][2] * inv);
            pk.w = f2bf(e[hh][3] * inv);
            *(ushort4*)&at[hh][ii][j0] = pk;
        }
    }
    __syncthreads();

    // ---- phase C: hp(16 x 512) = attn @ Wh, fp32 accumulate
    int half = t >> 7;
    int hh = (t >> 5) & 3;
    int fq = t & 31;
    float4 acc[8];
#pragma unroll
    for (int i = 0; i < 8; i++) acc[i] = make_float4(0.f, 0.f, 0.f, 0.f);
    const float4* whb = (const float4*)(Wh + ((size_t)b * HH + hh) * NN * OF);
    for (int jj = 0; jj < NN; jj += 2) {
        float4 w0 = whb[jj * 32 + fq];
        float4 w1 = whb[jj * 32 + 32 + fq];
#pragma unroll
        for (int i = 0; i < 8; i++) {
            unsigned a01 = *(const unsigned*)&at[hh][half * 8 + i][jj];
            float a0 = __uint_as_float(a01 << 16);
            float a1 = __uint_as_float(a01 & 0xffff0000u);
            acc[i].x += a0 * w0.x; acc[i].y += a0 * w0.y;
            acc[i].z += a0 * w0.z; acc[i].w += a0 * w0.w;
            acc[i].x += a1 * w1.x; acc[i].y += a1 * w1.y;
            acc[i].z += a1 * w1.z; acc[i].w += a1 * w1.w;
        }
    }
    __syncthreads();           // done reading attn
#pragma unroll
    for (int i = 0; i < 8; i++) {   // hp row layout: [16][516] (pad 4 floats -> bank shift)
        float* hr = big + (half * 8 + i) * 516 + hh * OF + fq * 4;
        *(float4*)hr = acc[i];
    }
    __syncthreads();

    // ---- phase D: out(16 x 128) = elu(hp @ Wc)
    int row = t >> 4, co = t & 15;
    const float* hr = big + row * 516;
    const float4* wc = (const float4*)Wc;
    float4 o0 = make_float4(0.f, 0.f, 0.f, 0.f);
    float4 o1 = make_float4(0.f, 0.f, 0.f, 0.f);
#pragma unroll 4
    for (int k = 0; k < 512; k++) {
        float hv = hr[k];
        float4 w0 = wc[k * 32 + co * 2];
        float4 w1 = wc[k * 32 + co * 2 + 1];
        o0.x += hv * w0.x; o0.y += hv * w0.y; o0.z += hv * w0.z; o0.w += hv * w0.w;
        o1.x += hv * w1.x; o1.y += hv * w1.y; o1.z += hv * w1.z; o1.w += hv * w1.w;
    }
    o0.x = o0.x > 0.f ? o0.x : expm1f(o0.x);
    o0.y = o0.y > 0.f ? o0.y : expm1f(o0.y);
    o0.z = o0.z > 0.f ? o0.z : expm1f(o0.z);
    o0.w = o0.w > 0.f ? o0.w : expm1f(o0.w);
    o1.x = o1.x > 0.f ? o1.x : expm1f(o1.x);
    o1.y = o1.y > 0.f ? o1.y : expm1f(o1.y);
    o1.z = o1.z > 0.f ? o1.z : expm1f(o1.z);
    o1.w = o1.w > 0.f ? o1.w : expm1f(o1.w);
    float* dst = out + ((size_t)b * NN + i0 + row) * OF + co * 8;
    *(float4*)dst = o0;
    *(float4*)(dst + 4) = o1;
}

extern "C" void kernel_launch(void* const* d_in, const int* in_sizes, int n_in,
                              void* d_out, int out_size, void* d_ws, size_t ws_size,
                              hipStream_t stream) {
    const float* h      = (const float*)d_in[0];
    const float* proj   = (const float*)d_in[1];
    const float* sim    = (const float*)d_in[2];
    const int*   qm     = (const int*)d_in[3];
    const float* W      = (const float*)d_in[4];
    const float* a      = (const float*)d_in[5];
    const float* w_proj = (const float*)d_in[6];
    const float* w_sim  = (const float*)d_in[7];
    const float* qbias  = (const float*)d_in[8];
    const float* Wc     = (const float*)d_in[9];
    float* out = (float*)d_out;

    const size_t whElems = (size_t)BB * HH * NN * OF;   // 8.39M
    float* Wh = (float*)d_ws;
    float* ei = Wh + whElems;
    float* ej = ei + (size_t)BB * HH * NN;
    float* sp = ej + (size_t)BB * HH * NN;
    float* ss = sp + (size_t)BB * HH * NN;

    k1_wh<<<BB * 16, 256, 0, stream>>>(h, W, a, w_proj, w_sim, Wh, ei, ej, sp, ss);
    k2_fused<<<BB * 16, 256, 0, stream>>>(proj, sim, qm, qbias, ei, ej, sp, ss, Wh, Wc, out);
}

// Round 3
// 182.358 us; speedup vs baseline: 1.9415x; 1.6872x over previous
//
#include <hip/hip_runtime.h>
#include <math.h>

#define BB 64
#define NN 256
#define IN_F 128
#define OF 128
#define HH 4
#define NEG_SLOPE 0.2f

typedef __attribute__((ext_vector_type(8))) short short8;
typedef __attribute__((ext_vector_type(4))) float f32x4;

#define MFMA16(a, b, c) __builtin_amdgcn_mfma_f32_16x16x32_bf16(a, b, c, 0, 0, 0)

// float -> bf16 bits, round-to-nearest-even (finite)
__device__ inline unsigned short f2bf(float x) {
    unsigned u = __float_as_uint(x);
    u += 0x7fff + ((u >> 16) & 1);
    return (unsigned short)(u >> 16);
}

// ---------------- K0: dtype conversions / transposes ----------------
// blocks [0,2048): h -> h_bf (bf16, same layout)
// blocks [2048,2064): W[k][512] -> Wt[f=512][k=128] bf16
// blocks [2064,2080): Wc[k][128] -> Wct[c=128][k=512] bf16
__global__ __launch_bounds__(256) void k0_convert(const float* __restrict__ h,
        const float* __restrict__ W, const float* __restrict__ Wc,
        unsigned short* __restrict__ h_bf, unsigned short* __restrict__ Wt,
        unsigned short* __restrict__ Wct) {
    int blk = blockIdx.x, t = threadIdx.x;
    if (blk < 2048) {
        int idx = blk * 256 + t;                 // float4 index, 524288 total
        float4 v = ((const float4*)h)[idx];
        ushort4 o;
        o.x = f2bf(v.x); o.y = f2bf(v.y); o.z = f2bf(v.z); o.w = f2bf(v.w);
        ((ushort4*)h_bf)[idx] = o;
    } else if (blk < 2064) {
        int base = (blk - 2048) * 4096 + t * 16;
#pragma unroll
        for (int e = 0; e < 16; e++) {
            int idx = base + e;                  // idx = f*128 + k
            int f = idx >> 7, k = idx & 127;
            Wt[idx] = f2bf(W[k * 512 + f]);
        }
    } else {
        int base = (blk - 2064) * 4096 + t * 16;
#pragma unroll
        for (int e = 0; e < 16; e++) {
            int idx = base + e;                  // idx = c*512 + k
            int c = idx >> 9, k = idx & 511;
            Wct[idx] = f2bf(Wc[k * 128 + c]);
        }
    }
}

// ---------------- K1: Wht = (h@W)^T via MFMA + fp32 per-node scalars ----------
// grid = B*4, block 256 (4 waves). Block: b = blk>>2, nodes n0..n0+63.
// Wave w handles head w (f-range w*128..w*128+127) for all 64 nodes.
// D' tile = Wt(16f x 32k) x h^T(32k x 16n): D'[f][n] = Wh[n][f].
__global__ __launch_bounds__(256) void k1_wh(const unsigned short* __restrict__ h_bf,
        const unsigned short* __restrict__ Wt, const float* __restrict__ a,
        const float* __restrict__ w_proj, const float* __restrict__ w_sim,
        unsigned short* __restrict__ Wht, float* __restrict__ ei,
        float* __restrict__ ej, float* __restrict__ sp, float* __restrict__ ss) {
    __shared__ float a1s[512], a2s[512], wps[128], wss[128];
    int blk = blockIdx.x;
    int b = blk >> 2;
    int n0 = (blk & 3) * 64;
    int t = threadIdx.x;
    for (int idx = t; idx < 512; idx += 256) {
        int hh = idx >> 7, f = idx & 127;
        a1s[idx] = a[hh * 256 + f];
        a2s[idx] = a[hh * 256 + 128 + f];
    }
    if (t < 128) { wps[t] = w_proj[t]; wss[t] = w_sim[t]; }
    __syncthreads();

    int w = t >> 6, lane = t & 63;
    int cc = lane & 15, g = lane >> 4;

    // B-frags: h^T[k][n], lane: col n = tn*16+cc, k = ks*32 + g*8 + e
    short8 bh[4][4];
#pragma unroll
    for (int tn = 0; tn < 4; tn++)
#pragma unroll
        for (int ks = 0; ks < 4; ks++)
            bh[tn][ks] = *(const short8*)(h_bf +
                ((size_t)(b * NN + n0 + tn * 16 + cc)) * IN_F + ks * 32 + g * 8);

    f32x4 acc[8][4];
#pragma unroll
    for (int tf = 0; tf < 8; tf++)
#pragma unroll
        for (int tn = 0; tn < 4; tn++) acc[tf][tn] = (f32x4)(0.f);

#pragma unroll
    for (int tf = 0; tf < 8; tf++) {
        short8 aw[4];   // A-frags: Wt[f][k], row f = w*128 + tf*16 + cc
#pragma unroll
        for (int ks = 0; ks < 4; ks++)
            aw[ks] = *(const short8*)(Wt +
                (size_t)(w * 128 + tf * 16 + cc) * IN_F + ks * 32 + g * 8);
#pragma unroll
        for (int tn = 0; tn < 4; tn++)
#pragma unroll
            for (int ks = 0; ks < 4; ks++)
                acc[tf][tn] = MFMA16(aw[ks], bh[tn][ks], acc[tf][tn]);
    }

    // store Wht bf16: D' row = f_out = tf*16 + g*4 + r, col = n = tn*16 + cc
    unsigned short* whb = Wht + (size_t)(b * HH + w) * OF * NN;
#pragma unroll
    for (int tf = 0; tf < 8; tf++)
#pragma unroll
        for (int r = 0; r < 4; r++) {
            int f = tf * 16 + g * 4 + r;
#pragma unroll
            for (int tn = 0; tn < 4; tn++)
                whb[(size_t)f * NN + n0 + tn * 16 + cc] = f2bf(acc[tf][tn][r]);
        }

    // fp32 scalars per node: dot over f (this lane covers f = tf*16+g*4+r)
#pragma unroll
    for (int tn = 0; tn < 4; tn++) {
        float q0 = 0.f, q1 = 0.f, q2 = 0.f, q3 = 0.f;
#pragma unroll
        for (int tf = 0; tf < 8; tf++)
#pragma unroll
            for (int r = 0; r < 4; r++) {
                float v = acc[tf][tn][r];
                int f = tf * 16 + g * 4 + r;
                q0 += v * a1s[w * 128 + f];
                q1 += v * a2s[w * 128 + f];
                q2 += v * wps[f];
                q3 += v * wss[f];
            }
        q0 += __shfl_xor(q0, 16); q0 += __shfl_xor(q0, 32);
        q1 += __shfl_xor(q1, 16); q1 += __shfl_xor(q1, 32);
        q2 += __shfl_xor(q2, 16); q2 += __shfl_xor(q2, 32);
        q3 += __shfl_xor(q3, 16); q3 += __shfl_xor(q3, 32);
        if (g == 0) {
            size_t idx = (size_t)(b * HH + w) * NN + n0 + tn * 16 + cc;
            ei[idx] = q0; ej[idx] = q1; sp[idx] = q2; ss[idx] = q3;
        }
    }
}

// ---------------- K2: e + softmax (wave-per-row) + MFMA PV + MFMA Wc + ELU ----
__global__ __launch_bounds__(256) void k2_fused(
        const float* __restrict__ proj, const float* __restrict__ sim,
        const int* __restrict__ qm, const float* __restrict__ qbias,
        const float* __restrict__ ei, const float* __restrict__ ej,
        const float* __restrict__ sp, const float* __restrict__ ss,
        const unsigned short* __restrict__ Wht, const unsigned short* __restrict__ Wct,
        float* __restrict__ out) {
    __shared__ __align__(16) char at_lds[32768];   // attn bf16 [4][16][256], XOR-swizzled rows
    __shared__ __align__(16) char hp_lds[16384];   // union: ejs f32[4][256] (phase B) / hp bf16[16][512] swizzled
    __shared__ float eis[HH][16], sps[HH][16], sss[HH][16];
    __shared__ float qb_s[16];
    float* ejs = (float*)hp_lds;

    int blk = blockIdx.x;                // B * 16
    int b = blk >> 4;
    int i0 = (blk & 15) * 16;
    int t = threadIdx.x;
    int wave = t >> 6, lane = t & 63;

    for (int c = t; c < HH * NN; c += 256)
        ejs[c] = ej[(size_t)b * HH * NN + c];
    if (t < 64) {
        int hh = t >> 4, ii = t & 15;
        size_t base = ((size_t)b * HH + hh) * NN + i0 + ii;
        eis[hh][ii] = ei[base]; sps[hh][ii] = sp[base]; sss[hh][ii] = ss[base];
    }
    if (t < 16) qb_s[t] = qbias[t];
    __syncthreads();

    // ---- phase B: wave owns rows wave*4..wave*4+3; lane owns j = lane*4..+3
    int j0 = lane * 4;
    for (int rr = 0; rr < 4; rr++) {
        int ii = wave * 4 + rr;
        int i = i0 + ii;
        size_t rb = ((size_t)b * NN + i) * NN + j0;
        float4 P4 = *(const float4*)&proj[rb];
        float4 S4 = *(const float4*)&sim[rb];
        int4 q0 = *(const int4*)&qm[rb * 2];
        int4 q1 = *(const int4*)&qm[rb * 2 + 4];
        float qb0 = qb_s[q0.x * 4 + q0.y], qb1 = qb_s[q0.z * 4 + q0.w];
        float qb2 = qb_s[q1.x * 4 + q1.y], qb3 = qb_s[q1.z * 4 + q1.w];
        float e[HH][4];
#pragma unroll
        for (int hh = 0; hh < HH; hh++) {
            float4 ej4 = *(const float4*)&ejs[hh * 256 + j0];
            float bi = eis[hh][ii], spv = sps[hh][ii], ssv = sss[hh][ii];
            float x;
            x = bi + ej4.x; x = x > 0.f ? x : NEG_SLOPE * x; e[hh][0] = x + spv * P4.x + ssv * S4.x + qb0;
            x = bi + ej4.y; x = x > 0.f ? x : NEG_SLOPE * x; e[hh][1] = x + spv * P4.y + ssv * S4.y + qb1;
            x = bi + ej4.z; x = x > 0.f ? x : NEG_SLOPE * x; e[hh][2] = x + spv * P4.z + ssv * S4.z + qb2;
            x = bi + ej4.w; x = x > 0.f ? x : NEG_SLOPE * x; e[hh][3] = x + spv * P4.w + ssv * S4.w + qb3;
        }
        float m[HH];
#pragma unroll
        for (int hh = 0; hh < HH; hh++)
            m[hh] = fmaxf(fmaxf(e[hh][0], e[hh][1]), fmaxf(e[hh][2], e[hh][3]));
#pragma unroll
        for (int off = 32; off; off >>= 1)
#pragma unroll
            for (int hh = 0; hh < HH; hh++)
                m[hh] = fmaxf(m[hh], __shfl_xor(m[hh], off));
        float s[HH];
#pragma unroll
        for (int hh = 0; hh < HH; hh++) {
            e[hh][0] = __expf(e[hh][0] - m[hh]);
            e[hh][1] = __expf(e[hh][1] - m[hh]);
            e[hh][2] = __expf(e[hh][2] - m[hh]);
            e[hh][3] = __expf(e[hh][3] - m[hh]);
            s[hh] = (e[hh][0] + e[hh][1]) + (e[hh][2] + e[hh][3]);
        }
#pragma unroll
        for (int off = 32; off; off >>= 1)
#pragma unroll
            for (int hh = 0; hh < HH; hh++) s[hh] += __shfl_xor(s[hh], off);
#pragma unroll
        for (int hh = 0; hh < HH; hh++) {
            float inv = 1.0f / s[hh];
            ushort4 pk;
            pk.x = f2bf(e[hh][0] * inv);
            pk.y = f2bf(e[hh][1] * inv);
            pk.z = f2bf(e[hh][2] * inv);
            pk.w = f2bf(e[hh][3] * inv);
            int off2 = hh * 8192 + ii * 512 + ((j0 * 2) ^ ((ii & 7) << 4));
            *(ushort4*)(at_lds + off2) = pk;
        }
    }
    __syncthreads();

    // ---- phase C: per wave (head w): hp[16 x 128] = attn[16 x 256] @ Wh[256 x 128]
    int w = wave;
    int row = lane & 15, g = lane >> 4;
    short8 af[8];
#pragma unroll
    for (int ks = 0; ks < 8; ks++) {
        int off = w * 8192 + row * 512 + ((((ks * 32 + g * 8) * 2)) ^ ((row & 7) << 4));
        af[ks] = *(const short8*)(at_lds + off);
    }
    f32x4 acc[8];
#pragma unroll
    for (int ft = 0; ft < 8; ft++) acc[ft] = (f32x4)(0.f);
    const unsigned short* whb = Wht + (size_t)(b * HH + w) * OF * NN;
#pragma unroll
    for (int ft = 0; ft < 8; ft++) {
        const unsigned short* wb = whb + (size_t)(ft * 16 + row) * NN + g * 8;
#pragma unroll
        for (int ks = 0; ks < 8; ks++) {
            short8 bf = *(const short8*)(wb + ks * 32);
            acc[ft] = MFMA16(af[ks], bf, acc[ft]);
        }
    }
    // hp -> bf16 LDS (swizzled rows of 1024B); i = g*4+r, kf = w*128 + ft*16 + row
#pragma unroll
    for (int ft = 0; ft < 8; ft++)
#pragma unroll
        for (int r = 0; r < 4; r++) {
            int i = g * 4 + r;
            int kf = w * 128 + ft * 16 + row;
            int off = i * 1024 + ((kf * 2) ^ ((i & 7) << 4));
            *(unsigned short*)(hp_lds + off) = f2bf(acc[ft][r]);
        }
    __syncthreads();

    // ---- phase D: out[16 x 128] = elu(hp[16 x 512] @ Wc[512 x 128])
    short8 ah[16];
#pragma unroll
    for (int ks = 0; ks < 16; ks++) {
        int off = row * 1024 + (((ks * 32 + g * 8) * 2) ^ ((row & 7) << 4));
        ah[ks] = *(const short8*)(hp_lds + off);
    }
    f32x4 o2[2];
    o2[0] = (f32x4)(0.f); o2[1] = (f32x4)(0.f);
#pragma unroll
    for (int ct = 0; ct < 2; ct++) {
        int c = (w * 2 + ct) * 16 + row;
        const unsigned short* wc = Wct + (size_t)c * 512 + g * 8;
#pragma unroll
        for (int ks = 0; ks < 16; ks++) {
            short8 bf = *(const short8*)(wc + ks * 32);
            o2[ct] = MFMA16(ah[ks], bf, o2[ct]);
        }
    }
#pragma unroll
    for (int ct = 0; ct < 2; ct++)
#pragma unroll
        for (int r = 0; r < 4; r++) {
            float v = o2[ct][r];
            v = v > 0.f ? v : expm1f(v);
            int i = i0 + g * 4 + r;
            int c = (w * 2 + ct) * 16 + row;
            out[((size_t)b * NN + i) * OF + c] = v;
        }
}

extern "C" void kernel_launch(void* const* d_in, const int* in_sizes, int n_in,
                              void* d_out, int out_size, void* d_ws, size_t ws_size,
                              hipStream_t stream) {
    const float* h      = (const float*)d_in[0];
    const float* proj   = (const float*)d_in[1];
    const float* sim    = (const float*)d_in[2];
    const int*   qm     = (const int*)d_in[3];
    const float* W      = (const float*)d_in[4];
    const float* a      = (const float*)d_in[5];
    const float* w_proj = (const float*)d_in[6];
    const float* w_sim  = (const float*)d_in[7];
    const float* qbias  = (const float*)d_in[8];
    const float* Wc     = (const float*)d_in[9];
    float* out = (float*)d_out;

    unsigned short* h_bf = (unsigned short*)d_ws;              // 2,097,152
    unsigned short* Wt   = h_bf + (size_t)BB * NN * IN_F;      // 65,536
    unsigned short* Wct  = Wt + 512 * 128;                     // 65,536
    unsigned short* Wht  = Wct + 128 * 512;                    // 8,388,608
    float* ei = (float*)(Wht + (size_t)BB * HH * OF * NN);
    float* ej = ei + (size_t)BB * HH * NN;
    float* sp = ej + (size_t)BB * HH * NN;
    float* ss = sp + (size_t)BB * HH * NN;

    k0_convert<<<2080, 256, 0, stream>>>(h, W, Wc, h_bf, Wt, Wct);
    k1_wh<<<BB * 4, 256, 0, stream>>>(h_bf, Wt, a, w_proj, w_sim, Wht, ei, ej, sp, ss);
    k2_fused<<<BB * 16, 256, 0, stream>>>(proj, sim, qm, qbias, ei, ej, sp, ss, Wht, Wct, out);
}